// Round 12
// baseline (408.162 us; speedup 1.0000x reference)
//
#include <hip/hip_runtime.h>
#include <hip/hip_bf16.h>
#include <float.h>

#define N_E   1024
#define CD    128
#define DELTA 0.32f

typedef __attribute__((ext_vector_type(4))) float f32x4;
typedef __attribute__((ext_vector_type(8))) short bf16x8;

static __device__ inline unsigned short f2bf(float f) {
    unsigned u = __float_as_uint(f);
    unsigned r = (u + 0x7fffu + ((u >> 16) & 1u)) >> 16;
    return (unsigned short)r;
}
static __device__ inline float bf2f(unsigned short s) {
    return __uint_as_float(((unsigned)s) << 16);
}

// ---------------- Kernel 1: embed = emb @ proj_w^T + b ; ee ; eperm (fragment-major bf16)
// eperm[(nt*4+ks)*512 + (hi2*16+lo4)*8 + e] = bf16(embed[nt*16+lo4][ks*32+hi2*8+e])
__global__ __launch_bounds__(128) void k_embed(const float* __restrict__ emb,
                                               const float* __restrict__ pw,
                                               const float* __restrict__ pb,
                                               float* __restrict__ embed,
                                               float* __restrict__ ee,
                                               unsigned short* __restrict__ eperm) {
    int j = blockIdx.x;
    int c = threadIdx.x;
    __shared__ float er[CD];
    __shared__ float red[CD];
    er[c] = emb[(size_t)j * CD + c];
    __syncthreads();
    float acc = pb[c];
    const float* pwr = pw + (size_t)c * CD;
    #pragma unroll 8
    for (int k = 0; k < CD; ++k) acc += er[k] * pwr[k];
    embed[(size_t)j * CD + c] = acc;
    const int nt  = j >> 4, lo4 = j & 15;
    const int ks  = c >> 5, hi2 = (c >> 3) & 3, e = c & 7;
    eperm[(size_t)(nt * 4 + ks) * 512 + (hi2 * 16 + lo4) * 8 + e] = f2bf(acc);
    red[c] = acc * acc;
    __syncthreads();
    for (int off = 64; off > 0; off >>= 1) {
        if (c < off) red[c] += red[c + off];
        __syncthreads();
    }
    if (c == 0) ee[j] = red[0];
}

// ---------------- Kernel 2: 4 waves M-split; B direct from L2 (fragment-major), no hot-loop sync
__global__ __launch_bounds__(256, 2) void k_vq(const float* __restrict__ x,
                                               const float* __restrict__ ee,
                                               const unsigned short* __restrict__ eperm,
                                               const float* __restrict__ embed,
                                               float* __restrict__ out_xq,
                                               float* __restrict__ out_idx,
                                               float* __restrict__ partials) {
    // region 32KB: x-tile [64 q][32 chunks of 8 bf16]: chunks 0-15 qhi, 16-31 qlo (offset +128);
    //   chunk ch of row m stored at (ch^SW(m)), SW(m)=(m&15)^(m>>4). Dead after A-frag
    //   extraction; aliased as recheck qbuf.
    __shared__ alignas(64) unsigned short region[64 * 256];
    __shared__ float ee_s[N_E];          // phase A alias: qqpart[16][64]
    __shared__ float qq[64];
    __shared__ int   bestjs[64];
    __shared__ unsigned flagm[4];

    const int t    = threadIdx.x;
    const int w    = t >> 6;             // 4 waves; wave owns queries [16w,16w+16)
    const int lane = t & 63;
    const int lo4  = lane & 15;
    const int hi2  = lane >> 4;
    const int blk  = blockIdx.x;
    const int qbase = blk * 64;
    const int b    = blk >> 4;           // 16 blocks per image
    const int hw0  = (blk & 15) * 64;
    const float* xb = x + (size_t)b * 131072;

    if (t < 4) flagm[t] = 0;

    const int f4 = t & 15;      // queries 4*f4 .. 4*f4+3
    const int cg = t >> 4;      // channel chunk cg: channels cg*8 .. cg*8+7

    // ---- phase A: stage x-tile as hi/lo bf16 (swizzled b128 writes) + qq partials
    {
        float4 v[8];
        #pragma unroll
        for (int r = 0; r < 8; ++r)
            v[r] = *reinterpret_cast<const float4*>(
                xb + (size_t)(cg * 8 + r) * 1024 + hw0 + 4 * f4);
        #pragma unroll
        for (int i = 0; i < 4; ++i) {
            const int m = 4 * f4 + i;
            const int sw = (m & 15) ^ (m >> 4);
            short hh[8], ll[8];
            float q2 = 0.f;
            #pragma unroll
            for (int r = 0; r < 8; ++r) {
                const float f = (&v[r].x)[i];
                q2 = fmaf(f, f, q2);
                const unsigned short hb = f2bf(f);
                hh[r] = (short)hb;
                ll[r] = (short)f2bf(f - bf2f(hb));
            }
            const int ch = cg ^ sw;
            *reinterpret_cast<bf16x8*>(&region[m * 256 + (ch << 3)]) =
                bf16x8{hh[0], hh[1], hh[2], hh[3], hh[4], hh[5], hh[6], hh[7]};
            *reinterpret_cast<bf16x8*>(&region[m * 256 + 128 + (ch << 3)]) =
                bf16x8{ll[0], ll[1], ll[2], ll[3], ll[4], ll[5], ll[6], ll[7]};
            ee_s[cg * 64 + m] = q2;   // qqpart alias
        }
    }
    __syncthreads();
    if (t < 64) {
        float s = 0.f;
        #pragma unroll
        for (int c2 = 0; c2 < 16; ++c2) s += ee_s[c2 * 64 + t];
        qq[t] = s;
    }
    __syncthreads();

    // ---- real ee_s, A-fragments into regs, per-lane qq
    for (int i = t; i < N_E; i += 256) ee_s[i] = ee[i];
    const int m_a = w * 16 + lo4;
    const int sw_a = lo4 ^ w;            // SW(m_a)
    bf16x8 a_hi[4], a_lo[4];
    #pragma unroll
    for (int ks = 0; ks < 4; ++ks) {
        const int kc = ks * 4 + hi2;
        a_hi[ks] = *reinterpret_cast<const bf16x8*>(&region[m_a * 256 + ((kc ^ sw_a) << 3)]);
        a_lo[ks] = *reinterpret_cast<const bf16x8*>(&region[m_a * 256 + 128 + ((kc ^ sw_a) << 3)]);
    }
    float qq_s[4];
    #pragma unroll
    for (int r = 0; r < 4; ++r) qq_s[r] = qq[w * 16 + hi2 * 4 + r];
    __syncthreads();    // region reads done (alias reuse later); ee_s ready

    // ---- hot loop: 64 n-tiles; B fragments straight from L2, coalesced; zero barriers
    float b1[4], b2[4], sacc[4];
    int   j1[4];
    #pragma unroll
    for (int s = 0; s < 4; ++s) { b1[s] = FLT_MAX; b2[s] = FLT_MAX; sacc[s] = 0.f; j1[s] = 0; }

    #pragma unroll 2
    for (int nt2 = 0; nt2 < 64; ++nt2) {
        const int n = nt2 * 16 + lo4;
        bf16x8 bfr[4];
        #pragma unroll
        for (int ks = 0; ks < 4; ++ks)
            bfr[ks] = *reinterpret_cast<const bf16x8*>(
                &eperm[(size_t)(nt2 * 4 + ks) * 512 + lane * 8]);
        const float ee_r = ee_s[n];
        f32x4 acc = {0.f, 0.f, 0.f, 0.f};
        #pragma unroll
        for (int ks = 0; ks < 4; ++ks) {
            acc = __builtin_amdgcn_mfma_f32_16x16x32_bf16(a_hi[ks], bfr[ks], acc, 0, 0, 0);
            acc = __builtin_amdgcn_mfma_f32_16x16x32_bf16(a_lo[ks], bfr[ks], acc, 0, 0, 0);
        }
        #pragma unroll
        for (int r = 0; r < 4; ++r) {
            float d2 = fmaf(-2.f, acc[r], qq_s[r] + ee_r);
            d2 = fmaxf(d2, 0.f);
            b2[r] = fminf(b2[r], fmaxf(b1[r], d2));
            const bool lt = d2 < b1[r];
            j1[r] = lt ? n : j1[r];
            b1[r] = lt ? d2 : b1[r];
            sacc[r] += __expf(16.f - sqrtf(d2));
        }
    }

    // ---- per-wave merge across lo4 (codes), flags, loss partial
    unsigned flagbits = 0;
    float lsum = 0.f;
    #pragma unroll
    for (int r = 0; r < 4; ++r) {
        float B1 = b1[r]; int J1 = j1[r]; float B2 = b2[r]; float S = sacc[r];
        #pragma unroll
        for (int d = 1; d <= 8; d <<= 1) {
            const float o1 = __shfl_xor(B1, d);
            const int   oj = __shfl_xor(J1, d);
            const float o2 = __shfl_xor(B2, d);
            const float os = __shfl_xor(S, d);
            const float mx = fmaxf(B1, o1);
            B2 = fminf(fminf(B2, o2), mx);
            const bool take = (o1 < B1) || (o1 == B1 && oj < J1);
            B1 = take ? o1 : B1;
            J1 = take ? oj : J1;
            S += os;
        }
        if (lo4 == 0) {
            const int mloc = hi2 * 4 + r;
            bestjs[w * 16 + mloc] = J1;
            out_idx[qbase + w * 16 + mloc] = (float)J1;
            if (B2 - B1 < DELTA) flagbits |= (1u << mloc);
            lsum += sqrtf(fmaxf(B1, 0.f)) - 16.f + __logf(S);
        }
    }
    if (lo4 == 0) atomicOr(&flagm[w], flagbits);
    lsum += __shfl_down(lsum, 16);
    lsum += __shfl_down(lsum, 32);
    if (lane == 0) partials[blk * 4 + w] = lsum;
    __syncthreads();

    // ---- exact fp32 recheck for near-tie queries (per wave, own rows)
    float* qbufw = reinterpret_cast<float*>(region) + w * 128;
    unsigned fm = flagm[w];
    while (fm) {
        const int mloc = __builtin_ctz(fm);
        fm &= fm - 1;
        const int m = w * 16 + mloc;
        const int hw = hw0 + m;
        qbufw[lane]      = xb[(size_t)lane * 1024 + hw];
        qbufw[64 + lane] = xb[(size_t)(lane + 64) * 1024 + hw];
        __threadfence_block();
        const float qqm = qq[m];
        float dbest = FLT_MAX; int jbest = 0;
        for (int tt = 0; tt < 16; ++tt) {
            const int j = tt * 64 + lane;
            float dot = 0.f;
            #pragma unroll 8
            for (int c4 = 0; c4 < 32; ++c4) {
                const f32x4 evv = *reinterpret_cast<const f32x4*>(&embed[j * CD + 4 * c4]);
                const f32x4 qv  = *reinterpret_cast<const f32x4*>(&qbufw[4 * c4]);
                dot = fmaf(evv[0], qv[0], dot);
                dot = fmaf(evv[1], qv[1], dot);
                dot = fmaf(evv[2], qv[2], dot);
                dot = fmaf(evv[3], qv[3], dot);
            }
            float d2 = fmaf(-2.f, dot, qqm + ee_s[j]);
            d2 = fmaxf(d2, 0.f);
            if (d2 < dbest || (d2 == dbest && j < jbest)) { dbest = d2; jbest = j; }
        }
        #pragma unroll
        for (int d = 1; d <= 32; d <<= 1) {
            const float od = __shfl_xor(dbest, d);
            const int   oj = __shfl_xor(jbest, d);
            if (od < dbest || (od == dbest && oj < jbest)) { dbest = od; jbest = oj; }
        }
        if (lane == 0) {
            bestjs[m] = jbest;
            out_idx[qbase + m] = (float)jbest;
        }
    }
    __syncthreads();

    // ---- gather x_q
    const int jq0 = bestjs[4 * f4 + 0];
    const int jq1 = bestjs[4 * f4 + 1];
    const int jq2 = bestjs[4 * f4 + 2];
    const int jq3 = bestjs[4 * f4 + 3];
    float* ob = out_xq + (size_t)b * 131072 + hw0 + 4 * f4;
    #pragma unroll
    for (int r = 0; r < 8; ++r) {
        const int c = cg * 8 + r;
        float4 v;
        v.x = embed[jq0 * CD + c];
        v.y = embed[jq1 * CD + c];
        v.z = embed[jq2 * CD + c];
        v.w = embed[jq3 * CD + c];
        *reinterpret_cast<float4*>(ob + (size_t)c * 1024) = v;
    }
}

// ---------------- Kernel 3: deterministic loss reduction
__global__ __launch_bounds__(256) void k_loss(const float* __restrict__ partials,
                                              float* __restrict__ out_loss) {
    __shared__ float red[256];
    const int t = threadIdx.x;
    float v = 0.f;
    for (int i = t; i < 4096; i += 256) v += partials[i];
    red[t] = v;
    __syncthreads();
    for (int off = 128; off; off >>= 1) {
        if (t < off) red[t] += red[t + off];
        __syncthreads();
    }
    if (t == 0) out_loss[0] = red[0] * (1.0f / 65536.0f);
}

extern "C" void kernel_launch(void* const* d_in, const int* in_sizes, int n_in,
                              void* d_out, int out_size, void* d_ws, size_t ws_size,
                              hipStream_t stream) {
    const float* x   = (const float*)d_in[0];   // (64,128,32,32)
    const float* emb = (const float*)d_in[1];   // (1024,128)
    const float* pw  = (const float*)d_in[2];   // (128,128)
    const float* pb  = (const float*)d_in[3];   // (128,)

    float* out = (float*)d_out;
    float* out_xq   = out;                 // 8388608 floats
    float* out_loss = out + 8388608;       // 1 float
    float* out_idx  = out + 8388609;       // 65536 floats

    float* embed    = (float*)d_ws;                       // 1024*128 fp32
    float* ee       = embed + N_E * CD;                   // 1024
    float* partials = ee + N_E;                           // 4096
    unsigned short* eperm = (unsigned short*)(partials + 4096);   // 1024*128 bf16, fragment-major

    k_embed<<<N_E, 128, 0, stream>>>(emb, pw, pb, embed, ee, eperm);
    k_vq<<<1024, 256, 0, stream>>>(x, ee, eperm, embed, out_xq, out_idx, partials);
    k_loss<<<1, 256, 0, stream>>>(partials, out_loss);
}

// Round 14
// 173.239 us; speedup vs baseline: 2.3561x; 2.3561x over previous
//
#include <hip/hip_runtime.h>
#include <hip/hip_bf16.h>
#include <float.h>

#define N_E   1024
#define CD    128
#define DELTA 0.01f

typedef __attribute__((ext_vector_type(4))) float f32x4;
typedef __attribute__((ext_vector_type(8))) short bf16x8;

static __device__ inline unsigned short f2bf(float f) {
    unsigned u = __float_as_uint(f);
    unsigned r = (u + 0x7fffu + ((u >> 16) & 1u)) >> 16;
    return (unsigned short)r;
}
static __device__ inline float bf2f(unsigned short s) {
    return __uint_as_float(((unsigned)s) << 16);
}

// ---------------- Kernel 1: embed = emb @ proj_w^T + b ; ee ; ehi/elo split bf16
__global__ __launch_bounds__(128) void k_embed(const float* __restrict__ emb,
                                               const float* __restrict__ pw,
                                               const float* __restrict__ pb,
                                               float* __restrict__ embed,
                                               float* __restrict__ ee,
                                               unsigned short* __restrict__ ehi,
                                               unsigned short* __restrict__ elo) {
    int j = blockIdx.x;
    int c = threadIdx.x;
    __shared__ float er[CD];
    __shared__ float red[CD];
    er[c] = emb[(size_t)j * CD + c];
    __syncthreads();
    float acc = pb[c];
    const float* pwr = pw + (size_t)c * CD;
    #pragma unroll 8
    for (int k = 0; k < CD; ++k) acc += er[k] * pwr[k];
    embed[(size_t)j * CD + c] = acc;
    const unsigned short h = f2bf(acc);
    const unsigned short l = f2bf(acc - bf2f(h));
    ehi[(size_t)j * CD + c] = h;
    elo[(size_t)j * CD + c] = l;
    red[c] = acc * acc;
    __syncthreads();
    for (int off = 64; off > 0; off >>= 1) {
        if (c < off) red[c] += red[c + off];
        __syncthreads();
    }
    if (c == 0) ee[j] = red[0];
}

// ---------------- Kernel 2: 8-wave M-split, 3-pass split-bf16 MFMA, 2-phase B dbuf
__global__ __launch_bounds__(512, 4) void k_vq(const float* __restrict__ x,
                                               const float* __restrict__ ee,
                                               const unsigned short* __restrict__ ehi,
                                               const unsigned short* __restrict__ elo,
                                               const float* __restrict__ embed,
                                               float* __restrict__ out_xq,
                                               float* __restrict__ out_idx,
                                               float* __restrict__ partials) {
    __shared__ alignas(64) unsigned short smem[2 * 16384];
    __shared__ float qq[128];
    __shared__ float qqpart[8][128];
    __shared__ float ee_s[N_E];
    __shared__ int   bestjs[128];
    __shared__ unsigned flagm[8];
    __shared__ alignas(16) float qbuf[8][128];

    const int t    = threadIdx.x;
    const int w    = t >> 6;          // 8 waves
    const int lane = t & 63;
    const int lo4  = lane & 15;
    const int hi2  = lane >> 4;
    const int blk  = blockIdx.x;
    const int qbase = blk * 128;
    const int b    = blk >> 3;
    const int hw0  = (blk & 7) * 128;
    const float* xb = x + (size_t)b * 131072;

    if (t < 8) flagm[t] = 0;
    for (int i = t; i < N_E; i += 512) ee_s[i] = ee[i];

    // ---- phase A: stage x-tile as hi/lo bf16 (swizzled b128 writes) + qq partials
    const int f4 = t & 31;            // queries 4*f4 .. 4*f4+3
    const int cg = t >> 5;            // channel chunk cg: channels cg*8 .. cg*8+7
    float4 xv[8];
    #pragma unroll
    for (int r = 0; r < 8; ++r)
        xv[r] = *reinterpret_cast<const float4*>(xb + (size_t)(cg * 8 + r) * 1024 + hw0 + 4 * f4);
    float qql[4] = {0.f, 0.f, 0.f, 0.f};
    #pragma unroll
    for (int i = 0; i < 4; ++i) {
        const int m = 4 * f4 + i;
        const int sw = (m & 15) ^ (m >> 4);
        short hh[8], ll[8];
        #pragma unroll
        for (int r = 0; r < 8; ++r) {
            const float f = (&xv[r].x)[i];
            qql[i] = fmaf(f, f, qql[i]);
            const unsigned short h = f2bf(f);
            hh[r] = (short)h;
            ll[r] = (short)f2bf(f - bf2f(h));
        }
        const int ch = cg ^ sw;
        *reinterpret_cast<bf16x8*>(&smem[m * 256 + (ch << 3)]) =
            bf16x8{hh[0], hh[1], hh[2], hh[3], hh[4], hh[5], hh[6], hh[7]};
        *reinterpret_cast<bf16x8*>(&smem[m * 256 + 128 + (ch << 3)]) =
            bf16x8{ll[0], ll[1], ll[2], ll[3], ll[4], ll[5], ll[6], ll[7]};
    }
    #pragma unroll
    for (int i = 0; i < 4; ++i) qql[i] += __shfl_xor(qql[i], 32);
    if (lane < 32) {
        #pragma unroll
        for (int i = 0; i < 4; ++i) qqpart[w][4 * lane + i] = qql[i];
    }
    __syncthreads();
    if (t < 128) {
        float s = 0.f;
        #pragma unroll
        for (int ww = 0; ww < 8; ++ww) s += qqpart[ww][t];
        qq[t] = s;
    }
    __syncthreads();

    // ---- A-fragments (qhi, qlo) into registers; wave owns queries mb..mb+15
    const int mb = w * 16;
    const int m_a = mb + lo4;
    const int sw_a = lo4 ^ w;         // SW(m) for m = w*16+lo4
    bf16x8 a_hi[4], a_lo[4];
    #pragma unroll
    for (int ks = 0; ks < 4; ++ks) {
        const int kc = ks * 4 + hi2;
        a_hi[ks] = *reinterpret_cast<const bf16x8*>(&smem[m_a * 256 + ((kc ^ sw_a) << 3)]);
        a_lo[ks] = *reinterpret_cast<const bf16x8*>(&smem[m_a * 256 + 128 + ((kc ^ sw_a) << 3)]);
    }
    float qq_s[4];
    #pragma unroll
    for (int r = 0; r < 4; ++r) qq_s[r] = qq[mb + hi2 * 4 + r];
    __syncthreads();   // all waves done reading x-region; safe to overwrite with B tiles

    // ---- B staging: global_load_lds width16, linear LDS dest, pre-swizzled global src
    auto stage = [&](int jb, int bufsel) {
        #pragma unroll
        for (int j = 0; j < 4; ++j) {
            const int base = w * 256 + j * 64;           // 64-chunk segment, wave-uniform
            const int cidx = base + lane;
            const int seg  = cidx >> 10;                 // 0: ehi, 1: elo
            const int rr   = cidx & 1023;
            const int n    = rr >> 4;
            const int s    = rr & 15;
            const int g    = s ^ (n & 15);
            const unsigned short* src = (seg ? elo : ehi) + (size_t)(jb + n) * CD + g * 8;
            unsigned short* dst = &smem[bufsel * 16384 + base * 8];  // wave-uniform
            __builtin_amdgcn_global_load_lds(
                (const __attribute__((address_space(1))) void*)src,
                (__attribute__((address_space(3))) void*)dst, 16, 0, 0);
        }
    };

    stage(0, 0);
    __syncthreads();   // buf0 ready

    float b1[4], b2[4], sacc[4];
    int   j1[4];
    #pragma unroll
    for (int s = 0; s < 4; ++s) { b1[s] = FLT_MAX; b2[s] = FLT_MAX; sacc[s] = 0.f; j1[s] = 0; }

    #pragma unroll 1
    for (int tile = 0; tile < 16; ++tile) {
        if (tile < 15) stage((tile + 1) * 64, (tile + 1) & 1);   // prefetch next buf

        const unsigned short* bb = &smem[(tile & 1) * 16384];
        const int jb = tile * 64;
        float ee_r[4];
        #pragma unroll
        for (int tn = 0; tn < 4; ++tn) ee_r[tn] = ee_s[jb + tn * 16 + lo4];

        f32x4 acc[4];
        const f32x4 zero = {0.f, 0.f, 0.f, 0.f};
        #pragma unroll
        for (int tn = 0; tn < 4; ++tn) acc[tn] = zero;

        // pass 0: qhi*ehi ; pass 1: qlo*ehi ; pass 2: qhi*elo
        #pragma unroll
        for (int p = 0; p < 3; ++p) {
            const int segoff = (p == 2) ? 8192 : 0;
            #pragma unroll
            for (int ks = 0; ks < 4; ++ks) {
                const int kc = ks * 4 + hi2;
                bf16x8 bfr[4];
                #pragma unroll
                for (int tn = 0; tn < 4; ++tn) {
                    const int n = tn * 16 + lo4;
                    bfr[tn] = *reinterpret_cast<const bf16x8*>(
                        &bb[segoff + n * CD + ((kc ^ (n & 15)) << 3)]);
                }
                #pragma unroll
                for (int tn = 0; tn < 4; ++tn)
                    acc[tn] = __builtin_amdgcn_mfma_f32_16x16x32_bf16(
                        (p == 1) ? a_lo[ks] : a_hi[ks], bfr[tn], acc[tn], 0, 0, 0);
            }
        }

        // ---- fold: d2 ; top-2 ; fixed-frame LSE
        #pragma unroll
        for (int tn = 0; tn < 4; ++tn) {
            const int n = jb + tn * 16 + lo4;
            #pragma unroll
            for (int r = 0; r < 4; ++r) {
                float d2 = fmaf(-2.f, acc[tn][r], qq_s[r] + ee_r[tn]);
                d2 = fmaxf(d2, 0.f);
                b2[r] = fminf(b2[r], fmaxf(b1[r], d2));
                const bool lt = d2 < b1[r];
                j1[r] = lt ? n : j1[r];
                b1[r] = lt ? d2 : b1[r];
                sacc[r] += __expf(16.f - sqrtf(d2));
            }
        }

        __syncthreads();   // drains prefetch vmcnt; all waves done reading bb
    }

    // ---- per-wave merge across lo4 (16 lanes share row), flags, loss partial
    unsigned flagbits = 0;
    float lsum = 0.f;
    #pragma unroll
    for (int r = 0; r < 4; ++r) {
        float B1 = b1[r]; int J1 = j1[r]; float B2 = b2[r]; float S = sacc[r];
        #pragma unroll
        for (int d = 1; d <= 8; d <<= 1) {
            const float o1 = __shfl_xor(B1, d);
            const int   oj = __shfl_xor(J1, d);
            const float o2 = __shfl_xor(B2, d);
            const float os = __shfl_xor(S, d);
            const float mx = fmaxf(B1, o1);
            B2 = fminf(fminf(B2, o2), mx);
            const bool take = (o1 < B1) || (o1 == B1 && oj < J1);
            B1 = take ? o1 : B1;
            J1 = take ? oj : J1;
            S += os;
        }
        if (lo4 == 0) {
            const int mloc = hi2 * 4 + r;
            bestjs[mb + mloc] = J1;
            out_idx[qbase + mb + mloc] = (float)J1;
            if (B2 - B1 < DELTA) flagbits |= (1u << mloc);
            lsum += sqrtf(fmaxf(B1, 0.f)) - 16.f + __logf(S);
        }
    }
    if (lo4 == 0) atomicOr(&flagm[w], flagbits);
    lsum += __shfl_down(lsum, 16);
    lsum += __shfl_down(lsum, 32);
    if (lane == 0) partials[blk * 8 + w] = lsum;
    __syncthreads();

    // ---- exact fp32 recheck for near-tie queries (per wave, own rows) — champion form
    unsigned fm = flagm[w];
    while (fm) {
        const int mloc = __builtin_ctz(fm);
        fm &= fm - 1;
        const int m = mb + mloc;
        const int hw = hw0 + m;
        qbuf[w][lane]      = xb[(size_t)lane * 1024 + hw];
        qbuf[w][64 + lane] = xb[(size_t)(lane + 64) * 1024 + hw];
        __threadfence_block();
        const float qqm = qq[m];
        float dbest = FLT_MAX; int jbest = 0;
        for (int tt = 0; tt < 16; ++tt) {
            const int j = tt * 64 + lane;
            float dot = 0.f;
            #pragma unroll 8
            for (int c4 = 0; c4 < 32; ++c4) {
                const f32x4 evv = *reinterpret_cast<const f32x4*>(&embed[j * CD + 4 * c4]);
                const f32x4 qv  = *reinterpret_cast<const f32x4*>(&qbuf[w][4 * c4]);
                dot = fmaf(evv[0], qv[0], dot);
                dot = fmaf(evv[1], qv[1], dot);
                dot = fmaf(evv[2], qv[2], dot);
                dot = fmaf(evv[3], qv[3], dot);
            }
            float d2 = fmaf(-2.f, dot, qqm + ee_s[j]);
            d2 = fmaxf(d2, 0.f);
            if (d2 < dbest || (d2 == dbest && j < jbest)) { dbest = d2; jbest = j; }
        }
        #pragma unroll
        for (int d = 1; d <= 32; d <<= 1) {
            const float od = __shfl_xor(dbest, d);
            const int   oj = __shfl_xor(jbest, d);
            if (od < dbest || (od == dbest && oj < jbest)) { dbest = od; jbest = oj; }
        }
        if (lane == 0) {
            bestjs[m] = jbest;
            out_idx[qbase + m] = (float)jbest;
        }
    }
    __syncthreads();

    // ---- gather x_q
    const int jq0 = bestjs[4 * f4 + 0];
    const int jq1 = bestjs[4 * f4 + 1];
    const int jq2 = bestjs[4 * f4 + 2];
    const int jq3 = bestjs[4 * f4 + 3];
    float* ob = out_xq + (size_t)b * 131072 + hw0 + 4 * f4;
    #pragma unroll
    for (int r = 0; r < 8; ++r) {
        const int c = cg * 8 + r;
        float4 v;
        v.x = embed[jq0 * CD + c];
        v.y = embed[jq1 * CD + c];
        v.z = embed[jq2 * CD + c];
        v.w = embed[jq3 * CD + c];
        *reinterpret_cast<float4*>(ob + (size_t)c * 1024) = v;
    }
}

// ---------------- Kernel 3: deterministic loss reduction
__global__ __launch_bounds__(256) void k_loss(const float* __restrict__ partials,
                                              float* __restrict__ out_loss) {
    __shared__ float red[256];
    const int t = threadIdx.x;
    float v = 0.f;
    for (int i = t; i < 4096; i += 256) v += partials[i];
    red[t] = v;
    __syncthreads();
    for (int off = 128; off; off >>= 1) {
        if (t < off) red[t] += red[t + off];
        __syncthreads();
    }
    if (t == 0) out_loss[0] = red[0] * (1.0f / 65536.0f);
}

extern "C" void kernel_launch(void* const* d_in, const int* in_sizes, int n_in,
                              void* d_out, int out_size, void* d_ws, size_t ws_size,
                              hipStream_t stream) {
    const float* x   = (const float*)d_in[0];   // (64,128,32,32)
    const float* emb = (const float*)d_in[1];   // (1024,128)
    const float* pw  = (const float*)d_in[2];   // (128,128)
    const float* pb  = (const float*)d_in[3];   // (128,)

    float* out = (float*)d_out;
    float* out_xq   = out;                 // 8388608 floats
    float* out_loss = out + 8388608;       // 1 float
    float* out_idx  = out + 8388609;       // 65536 floats

    float* embed    = (float*)d_ws;                       // 1024*128 fp32
    float* ee       = embed + N_E * CD;                   // 1024
    float* partials = ee + N_E;                           // 4096
    unsigned short* ehi = (unsigned short*)(partials + 4096);   // 1024*128 bf16
    unsigned short* elo = ehi + N_E * CD;                       // 1024*128 bf16

    k_embed<<<N_E, 128, 0, stream>>>(emb, pw, pb, embed, ee, ehi, elo);
    k_vq<<<512, 512, 0, stream>>>(x, ee, ehi, elo, embed, out_xq, out_idx, partials);
    k_loss<<<1, 256, 0, stream>>>(partials, out_loss);
}

// Round 15
// 137.442 us; speedup vs baseline: 2.9697x; 1.2605x over previous
//
#include <hip/hip_runtime.h>
#include <hip/hip_bf16.h>
#include <float.h>

#define N_E   1024
#define CD    128
#define DELTA 0.01f

typedef __attribute__((ext_vector_type(4))) float f32x4;
typedef __attribute__((ext_vector_type(8))) short bf16x8;

static __device__ inline unsigned short f2bf(float f) {
    unsigned u = __float_as_uint(f);
    unsigned r = (u + 0x7fffu + ((u >> 16) & 1u)) >> 16;
    return (unsigned short)r;
}
static __device__ inline float bf2f(unsigned short s) {
    return __uint_as_float(((unsigned)s) << 16);
}

// ---------------- Kernel 1: embed = emb @ proj_w^T + b ; ee ; ehi/elo split bf16
__global__ __launch_bounds__(128) void k_embed(const float* __restrict__ emb,
                                               const float* __restrict__ pw,
                                               const float* __restrict__ pb,
                                               float* __restrict__ embed,
                                               float* __restrict__ ee,
                                               unsigned short* __restrict__ ehi,
                                               unsigned short* __restrict__ elo) {
    int j = blockIdx.x;
    int c = threadIdx.x;
    __shared__ float er[CD];
    __shared__ float red[CD];
    er[c] = emb[(size_t)j * CD + c];
    __syncthreads();
    float acc = pb[c];
    const float* pwr = pw + (size_t)c * CD;
    #pragma unroll 8
    for (int k = 0; k < CD; ++k) acc += er[k] * pwr[k];
    embed[(size_t)j * CD + c] = acc;
    const unsigned short h = f2bf(acc);
    const unsigned short l = f2bf(acc - bf2f(h));
    ehi[(size_t)j * CD + c] = h;
    elo[(size_t)j * CD + c] = l;
    red[c] = acc * acc;
    __syncthreads();
    for (int off = 64; off > 0; off >>= 1) {
        if (c < off) red[c] += red[c + off];
        __syncthreads();
    }
    if (c == 0) ee[j] = red[0];
}

// ---------------- Kernel 2: 4 waves, tm=2 (32 rows/wave), hoisted ehi reads, 3-pass MFMA
__global__ __launch_bounds__(256, 4) void k_vq(const float* __restrict__ x,
                                               const float* __restrict__ ee,
                                               const unsigned short* __restrict__ ehi,
                                               const unsigned short* __restrict__ elo,
                                               const float* __restrict__ embed,
                                               float* __restrict__ out_xq,
                                               float* __restrict__ out_idx,
                                               float* __restrict__ partials) {
    // Phase 1: smem = x-tile [128 rows][32 chunks of 8 shorts], chunk cc at cc^SW(m),
    //          SW(m) = (m&15)^(m>>4); chunks 0-15 qhi, 16-31 qlo (offset +128 shorts).
    // Phase 2: smem = B dbuf, each buf 16384 shorts = ehi[64][128] + elo[64][128];
    //          LDS slot s of row n holds global chunk s^(n&15) (linear dest, swizzled src).
    __shared__ alignas(64) unsigned short smem[2 * 16384];
    __shared__ float qq[128];
    __shared__ float qqpart[4][128];
    __shared__ float ee_s[N_E];
    __shared__ int   bestjs[128];
    __shared__ unsigned flagm[4];
    __shared__ alignas(16) float qbuf[4][128];

    const int t    = threadIdx.x;
    const int w    = t >> 6;          // 4 waves; wave owns queries [32w, 32w+32)
    const int lane = t & 63;
    const int lo4  = lane & 15;
    const int hi2  = lane >> 4;
    const int blk  = blockIdx.x;
    const int qbase = blk * 128;
    const int b    = blk >> 3;
    const int hw0  = (blk & 7) * 128;
    const float* xb = x + (size_t)b * 131072;

    if (t < 4) flagm[t] = 0;
    for (int i = t; i < N_E; i += 256) ee_s[i] = ee[i];

    // ---- phase A: stage x-tile as hi/lo bf16 (swizzled b128 writes) + qq partials
    const int f4 = t & 31;            // queries 4*f4 .. 4*f4+3
    const int cg = t >> 5;            // 0..7: channels cg*16 .. cg*16+15
    float4 xv[16];
    #pragma unroll
    for (int r = 0; r < 16; ++r)
        xv[r] = *reinterpret_cast<const float4*>(
            xb + (size_t)(cg * 16 + r) * 1024 + hw0 + 4 * f4);
    float qql[4] = {0.f, 0.f, 0.f, 0.f};
    #pragma unroll
    for (int i = 0; i < 4; ++i) {
        const int m = 4 * f4 + i;
        const int sw = (m & 15) ^ (m >> 4);
        short hh[16], ll[16];
        #pragma unroll
        for (int r = 0; r < 16; ++r) {
            const float f = (&xv[r].x)[i];
            qql[i] = fmaf(f, f, qql[i]);
            const unsigned short h = f2bf(f);
            hh[r] = (short)h;
            ll[r] = (short)f2bf(f - bf2f(h));
        }
        const int ch0 = (2 * cg) ^ sw;
        const int ch1 = (2 * cg + 1) ^ sw;
        *reinterpret_cast<bf16x8*>(&smem[m * 256 + (ch0 << 3)]) =
            bf16x8{hh[0], hh[1], hh[2], hh[3], hh[4], hh[5], hh[6], hh[7]};
        *reinterpret_cast<bf16x8*>(&smem[m * 256 + (ch1 << 3)]) =
            bf16x8{hh[8], hh[9], hh[10], hh[11], hh[12], hh[13], hh[14], hh[15]};
        *reinterpret_cast<bf16x8*>(&smem[m * 256 + 128 + (ch0 << 3)]) =
            bf16x8{ll[0], ll[1], ll[2], ll[3], ll[4], ll[5], ll[6], ll[7]};
        *reinterpret_cast<bf16x8*>(&smem[m * 256 + 128 + (ch1 << 3)]) =
            bf16x8{ll[8], ll[9], ll[10], ll[11], ll[12], ll[13], ll[14], ll[15]};
    }
    #pragma unroll
    for (int i = 0; i < 4; ++i) qql[i] += __shfl_xor(qql[i], 32);
    if (lane < 32) {
        #pragma unroll
        for (int i = 0; i < 4; ++i) qqpart[w][4 * lane + i] = qql[i];
    }
    __syncthreads();
    if (t < 128) {
        float s = 0.f;
        #pragma unroll
        for (int ww = 0; ww < 4; ++ww) s += qqpart[ww][t];
        qq[t] = s;
    }
    __syncthreads();

    // ---- A-fragments (qhi, qlo) into registers; wave owns rows mb..mb+31
    const int mb = w * 32;
    bf16x8 a_hi[2][4], a_lo[2][4];
    #pragma unroll
    for (int tm = 0; tm < 2; ++tm) {
        const int m = mb + tm * 16 + lo4;
        const int sw = lo4 ^ (2 * w + tm);   // SW(m)
        #pragma unroll
        for (int ks = 0; ks < 4; ++ks) {
            const int kc = ks * 4 + hi2;
            a_hi[tm][ks] = *reinterpret_cast<const bf16x8*>(&smem[m * 256 + ((kc ^ sw) << 3)]);
            a_lo[tm][ks] = *reinterpret_cast<const bf16x8*>(&smem[m * 256 + 128 + ((kc ^ sw) << 3)]);
        }
    }
    float qq_s[8];
    #pragma unroll
    for (int tm = 0; tm < 2; ++tm)
        #pragma unroll
        for (int r = 0; r < 4; ++r) qq_s[tm * 4 + r] = qq[mb + tm * 16 + hi2 * 4 + r];
    __syncthreads();   // all waves done reading x-region; safe to overwrite with B tiles

    // ---- B staging: global_load_lds width16, linear LDS dest, pre-swizzled global src
    auto stage = [&](int jb, int bufsel) {
        #pragma unroll
        for (int j = 0; j < 8; ++j) {
            const int base = w * 512 + j * 64;           // 64-chunk segment, wave-uniform
            const int cidx = base + lane;
            const int seg  = cidx >> 10;                 // 0: ehi, 1: elo
            const int rr   = cidx & 1023;
            const int n    = rr >> 4;
            const int s    = rr & 15;
            const int g    = s ^ (n & 15);
            const unsigned short* src = (seg ? elo : ehi) + (size_t)(jb + n) * CD + g * 8;
            unsigned short* dst = &smem[bufsel * 16384 + base * 8];  // wave-uniform
            __builtin_amdgcn_global_load_lds(
                (const __attribute__((address_space(1))) void*)src,
                (__attribute__((address_space(3))) void*)dst, 16, 0, 0);
        }
    };

    stage(0, 0);
    __syncthreads();   // buf0 ready

    float b1[8], b2[8], sacc[8];
    int   j1[8];
    #pragma unroll
    for (int s = 0; s < 8; ++s) { b1[s] = FLT_MAX; b2[s] = FLT_MAX; sacc[s] = 0.f; j1[s] = 0; }

    #pragma unroll 1
    for (int tile = 0; tile < 16; ++tile) {
        if (tile < 15) stage((tile + 1) * 64, (tile + 1) & 1);   // prefetch next buf

        const unsigned short* bb = &smem[(tile & 1) * 16384];
        const int jb = tile * 64;
        float ee_r[4];
        #pragma unroll
        for (int tn = 0; tn < 4; ++tn) ee_r[tn] = ee_s[jb + tn * 16 + lo4];

        f32x4 acc[2][4];
        const f32x4 zero = {0.f, 0.f, 0.f, 0.f};
        #pragma unroll
        for (int tm = 0; tm < 2; ++tm)
            #pragma unroll
            for (int tn = 0; tn < 4; ++tn) acc[tm][tn] = zero;

        // ehi fragments: read ONCE, apply qhi (p0) and qlo (p1)
        #pragma unroll
        for (int ks = 0; ks < 4; ++ks) {
            const int kc = ks * 4 + hi2;
            bf16x8 bh[4];
            #pragma unroll
            for (int tn = 0; tn < 4; ++tn) {
                const int n = tn * 16 + lo4;
                bh[tn] = *reinterpret_cast<const bf16x8*>(
                    &bb[n * CD + ((kc ^ (n & 15)) << 3)]);
            }
            #pragma unroll
            for (int tn = 0; tn < 4; ++tn)
                #pragma unroll
                for (int tm = 0; tm < 2; ++tm) {
                    acc[tm][tn] = __builtin_amdgcn_mfma_f32_16x16x32_bf16(a_hi[tm][ks], bh[tn], acc[tm][tn], 0, 0, 0);
                    acc[tm][tn] = __builtin_amdgcn_mfma_f32_16x16x32_bf16(a_lo[tm][ks], bh[tn], acc[tm][tn], 0, 0, 0);
                }
        }
        // elo fragments: qhi only (p2)
        #pragma unroll
        for (int ks = 0; ks < 4; ++ks) {
            const int kc = ks * 4 + hi2;
            bf16x8 bl[4];
            #pragma unroll
            for (int tn = 0; tn < 4; ++tn) {
                const int n = tn * 16 + lo4;
                bl[tn] = *reinterpret_cast<const bf16x8*>(
                    &bb[8192 + n * CD + ((kc ^ (n & 15)) << 3)]);
            }
            #pragma unroll
            for (int tn = 0; tn < 4; ++tn)
                #pragma unroll
                for (int tm = 0; tm < 2; ++tm)
                    acc[tm][tn] = __builtin_amdgcn_mfma_f32_16x16x32_bf16(a_hi[tm][ks], bl[tn], acc[tm][tn], 0, 0, 0);
        }

        // ---- fold: d2 ; top-2 ; fixed-frame LSE
        #pragma unroll
        for (int tm = 0; tm < 2; ++tm)
            #pragma unroll
            for (int tn = 0; tn < 4; ++tn) {
                const int n = jb + tn * 16 + lo4;
                #pragma unroll
                for (int r = 0; r < 4; ++r) {
                    const int slot = tm * 4 + r;
                    float d2 = fmaf(-2.f, acc[tm][tn][r], qq_s[slot] + ee_r[tn]);
                    d2 = fmaxf(d2, 0.f);
                    b2[slot] = fminf(b2[slot], fmaxf(b1[slot], d2));
                    const bool lt = d2 < b1[slot];
                    j1[slot] = lt ? n : j1[slot];
                    b1[slot] = lt ? d2 : b1[slot];
                    float sd;
                    asm("v_sqrt_f32 %0, %1" : "=v"(sd) : "v"(d2));
                    sacc[slot] += __expf(16.f - sd);
                }
            }

        __syncthreads();   // drains prefetch vmcnt; all waves done reading bb
    }

    // ---- per-wave merge across lo4 (codes), flags, loss partial
    unsigned flagbits = 0;
    float lsum = 0.f;
    #pragma unroll
    for (int slot = 0; slot < 8; ++slot) {
        float B1 = b1[slot]; int J1 = j1[slot]; float B2 = b2[slot]; float S = sacc[slot];
        #pragma unroll
        for (int d = 1; d <= 8; d <<= 1) {
            const float o1 = __shfl_xor(B1, d);
            const int   oj = __shfl_xor(J1, d);
            const float o2 = __shfl_xor(B2, d);
            const float os = __shfl_xor(S, d);
            const float mx = fmaxf(B1, o1);
            B2 = fminf(fminf(B2, o2), mx);
            const bool take = (o1 < B1) || (o1 == B1 && oj < J1);
            B1 = take ? o1 : B1;
            J1 = take ? oj : J1;
            S += os;
        }
        if (lo4 == 0) {
            const int mloc = (slot >> 2) * 16 + hi2 * 4 + (slot & 3);
            bestjs[mb + mloc] = J1;
            out_idx[qbase + mb + mloc] = (float)J1;
            if (B2 - B1 < DELTA) flagbits |= (1u << mloc);
            lsum += sqrtf(fmaxf(B1, 0.f)) - 16.f + __logf(S);
        }
    }
    if (lo4 == 0) atomicOr(&flagm[w], flagbits);
    lsum += __shfl_down(lsum, 16);
    lsum += __shfl_down(lsum, 32);
    if (lane == 0) partials[blk * 4 + w] = lsum;
    __syncthreads();

    // ---- exact fp32 recheck for near-tie queries (per wave, own rows) — champion form
    unsigned fm = flagm[w];
    while (fm) {
        const int mloc = __builtin_ctz(fm);
        fm &= fm - 1;
        const int m = mb + mloc;
        const int hw = hw0 + m;
        qbuf[w][lane]      = xb[(size_t)lane * 1024 + hw];
        qbuf[w][64 + lane] = xb[(size_t)(lane + 64) * 1024 + hw];
        __threadfence_block();
        const float qqm = qq[m];
        float dbest = FLT_MAX; int jbest = 0;
        for (int tt = 0; tt < 16; ++tt) {
            const int j = tt * 64 + lane;
            float dot = 0.f;
            #pragma unroll 8
            for (int c4 = 0; c4 < 32; ++c4) {
                const f32x4 evv = *reinterpret_cast<const f32x4*>(&embed[j * CD + 4 * c4]);
                const f32x4 qv  = *reinterpret_cast<const f32x4*>(&qbuf[w][4 * c4]);
                dot = fmaf(evv[0], qv[0], dot);
                dot = fmaf(evv[1], qv[1], dot);
                dot = fmaf(evv[2], qv[2], dot);
                dot = fmaf(evv[3], qv[3], dot);
            }
            float d2 = fmaf(-2.f, dot, qqm + ee_s[j]);
            d2 = fmaxf(d2, 0.f);
            if (d2 < dbest || (d2 == dbest && j < jbest)) { dbest = d2; jbest = j; }
        }
        #pragma unroll
        for (int d = 1; d <= 32; d <<= 1) {
            const float od = __shfl_xor(dbest, d);
            const int   oj = __shfl_xor(jbest, d);
            if (od < dbest || (od == dbest && oj < jbest)) { dbest = od; jbest = oj; }
        }
        if (lane == 0) {
            bestjs[m] = jbest;
            out_idx[qbase + m] = (float)jbest;
        }
    }
    __syncthreads();

    // ---- gather x_q
    const int jq0 = bestjs[4 * f4 + 0];
    const int jq1 = bestjs[4 * f4 + 1];
    const int jq2 = bestjs[4 * f4 + 2];
    const int jq3 = bestjs[4 * f4 + 3];
    float* ob = out_xq + (size_t)b * 131072 + hw0 + 4 * f4;
    #pragma unroll
    for (int r = 0; r < 16; ++r) {
        const int c = cg * 16 + r;
        float4 v;
        v.x = embed[jq0 * CD + c];
        v.y = embed[jq1 * CD + c];
        v.z = embed[jq2 * CD + c];
        v.w = embed[jq3 * CD + c];
        *reinterpret_cast<float4*>(ob + (size_t)c * 1024) = v;
    }
}

// ---------------- Kernel 3: deterministic loss reduction
__global__ __launch_bounds__(256) void k_loss(const float* __restrict__ partials,
                                              float* __restrict__ out_loss) {
    __shared__ float red[256];
    const int t = threadIdx.x;
    float v = 0.f;
    for (int i = t; i < 2048; i += 256) v += partials[i];
    red[t] = v;
    __syncthreads();
    for (int off = 128; off; off >>= 1) {
        if (t < off) red[t] += red[t + off];
        __syncthreads();
    }
    if (t == 0) out_loss[0] = red[0] * (1.0f / 65536.0f);
}

extern "C" void kernel_launch(void* const* d_in, const int* in_sizes, int n_in,
                              void* d_out, int out_size, void* d_ws, size_t ws_size,
                              hipStream_t stream) {
    const float* x   = (const float*)d_in[0];   // (64,128,32,32)
    const float* emb = (const float*)d_in[1];   // (1024,128)
    const float* pw  = (const float*)d_in[2];   // (128,128)
    const float* pb  = (const float*)d_in[3];   // (128,)

    float* out = (float*)d_out;
    float* out_xq   = out;                 // 8388608 floats
    float* out_loss = out + 8388608;       // 1 float
    float* out_idx  = out + 8388609;       // 65536 floats

    float* embed    = (float*)d_ws;                       // 1024*128 fp32
    float* ee       = embed + N_E * CD;                   // 1024
    float* partials = ee + N_E;                           // 2048
    unsigned short* ehi = (unsigned short*)(partials + 2048);   // 1024*128 bf16
    unsigned short* elo = ehi + N_E * CD;                       // 1024*128 bf16

    k_embed<<<N_E, 128, 0, stream>>>(emb, pw, pb, embed, ee, ehi, elo);
    k_vq<<<512, 256, 0, stream>>>(x, ee, ehi, elo, embed, out_xq, out_idx, partials);
    k_loss<<<1, 256, 0, stream>>>(partials, out_loss);
}